// Round 7
// baseline (595.884 us; speedup 1.0000x reference)
//
#include <hip/hip_runtime.h>
#include <hip/hip_bf16.h>

#define NB    16
#define CIN   512
#define COUT  512
#define HH    64
#define WW    64
#define HWSZ  4096
#define WDIMN 512

typedef __attribute__((ext_vector_type(8))) short bf16x8;
typedef __attribute__((ext_vector_type(4))) float f32x4;

__device__ __forceinline__ unsigned short f2bf(float f) {
    unsigned int u = __float_as_uint(f);
    unsigned int lsb = (u >> 16) & 1u;
    u += 0x7fffu + lsb;               // round-to-nearest-even (finite inputs)
    return (unsigned short)(u >> 16);
}

__device__ __forceinline__ void gload_lds16(const void* g, void* l) {
    __builtin_amdgcn_global_load_lds(
        (const __attribute__((address_space(1))) unsigned char*)g,
        (__attribute__((address_space(3))) unsigned char*)l,
        16, 0, 0);
}

// ---------------- k1: style[b][ci] = coef_mod * (w @ mod_w) + mod_b + 1 ----------------
__global__ void k_style(const float* __restrict__ w, const float* __restrict__ mod_w,
                        const float* __restrict__ mod_b, float* __restrict__ style) {
    const int b = blockIdx.x, t = threadIdx.x;
    __shared__ float wl[WDIMN];
    wl[t] = w[b * WDIMN + t];
    wl[t + 256] = w[b * WDIMN + t + 256];
    __syncthreads();
    float a0 = 0.f, a1 = 0.f;
    const int c0 = t, c1 = t + 256;
    for (int j = 0; j < WDIMN; ++j) {
        const float wj = wl[j];
        a0 += wj * mod_w[j * CIN + c0];
        a1 += wj * mod_w[j * CIN + c1];
    }
    const float coef = 0.044194173824159216f; // 1/sqrt(512)
    style[b * CIN + c0] = coef * a0 + mod_b[c0] + 1.0f;
    style[b * CIN + c1] = coef * a1 + mod_b[c1] + 1.0f;
}

// ---------------- k2: s2[ci][co] = sum_taps conv_w^2 ----------------
__global__ void k_s2(const float* __restrict__ cw, float* __restrict__ s2) {
    const int i = blockIdx.x * 256 + threadIdx.x; // [ci*512+co]
    float a = 0.f;
#pragma unroll
    for (int tap = 0; tap < 9; ++tap) {
        const float v = cw[tap * (CIN * COUT) + i];
        a += v * v;
    }
    s2[i] = a;
}

// ---------------- k3: d[b][co] = rsqrt(coef^2 * sum_ci style^2 * s2 + 1e-8) ----------------
__global__ void k_demod(const float* __restrict__ style, const float* __restrict__ s2,
                        float* __restrict__ dd) {
    const int b = blockIdx.x, t = threadIdx.x;
    __shared__ float st2[CIN];
    {
        const float s0 = style[b * CIN + t], s1 = style[b * CIN + t + 256];
        st2[t] = s0 * s0;
        st2[t + 256] = s1 * s1;
    }
    __syncthreads();
    float a0 = 0.f, a1 = 0.f;
    for (int ci = 0; ci < CIN; ++ci) {
        const float sv = st2[ci];
        a0 += sv * s2[ci * COUT + t];
        a1 += sv * s2[ci * COUT + t + 256];
    }
    const float c2 = 1.0f / 4608.0f; // coef_conv^2
    dd[b * COUT + t] = rsqrtf(c2 * a0 + 1e-8f);
    dd[b * COUT + t + 256] = rsqrtf(c2 * a1 + 1e-8f);
}

// ---------------- k4: pre-fragmented modulated weight ----------------
// afrag element offset = ((((((bbl*9+tap)*4+ct)*8+cc2)*2+k32)*8+rg)*64 + hi*16+lo)*8 + j
// where co = ct*128 + rg*16 + lo, ci = cc2*64 + k32*32 + hi*8 + j.
// A wave's MFMA A-frag load is then one fully-coalesced 1KB global_load_dwordx4.
__global__ void k_wmod(const float* __restrict__ cw, const float* __restrict__ style,
                       const float* __restrict__ dd, unsigned short* __restrict__ wmod,
                       int b_start, int gcount) {
    const int tap = blockIdx.x;
    const int co0 = blockIdx.y * 64;
    const int ci0 = blockIdx.z * 128;
    const int t = threadIdx.x;

    __shared__ float tile[128][65]; // [ci][co], padded
    __shared__ float sst[16 * 128]; // style slice [bbl][128-ci-chunk]
    {
        const int j = t & 63, isub = t >> 6;
        for (int i = isub; i < 128; i += 4)
            tile[i][j] = cw[(size_t)tap * CIN * COUT + (size_t)(ci0 + i) * COUT + co0 + j];
    }
    for (int i = t; i < gcount * 128; i += 256)
        sst[i] = style[(b_start + (i >> 7)) * CIN + ci0 + (i & 127)];
    __syncthreads();

    const float coef = 0.014731391274719736f; // 1/sqrt(4608)
    const int cq = t & 31;        // ci quad: ci = ci0 + 4*cq + k
    const int rsub = t >> 5;      // 0..7
    const int totrows = gcount * 64;
    for (int g = rsub; g < totrows; g += 8) {
        const int bbl = g >> 6;
        const int co_r = g & 63;
        const int bg = b_start + bbl;
        const float dv = dd[bg * COUT + co0 + co_r] * coef;
        const float v0 = tile[4 * cq + 0][co_r] * sst[bbl * 128 + 4 * cq + 0] * dv;
        const float v1 = tile[4 * cq + 1][co_r] * sst[bbl * 128 + 4 * cq + 1] * dv;
        const float v2 = tile[4 * cq + 2][co_r] * sst[bbl * 128 + 4 * cq + 2] * dv;
        const float v3 = tile[4 * cq + 3][co_r] * sst[bbl * 128 + 4 * cq + 3] * dv;
        uint2 pk;
        pk.x = (unsigned int)f2bf(v0) | ((unsigned int)f2bf(v1) << 16);
        pk.y = (unsigned int)f2bf(v2) | ((unsigned int)f2bf(v3) << 16);
        // fragment-layout store
        const int co_g = co0 + co_r;
        const int ct4 = co_g >> 7;
        const int rg  = (co_g >> 4) & 7;
        const int lo  = co_g & 15;
        const int ci_g = ci0 + 4 * cq;
        const int cc2 = ci_g >> 6;
        const int k32 = (ci_g >> 5) & 1;
        const int hi  = (ci_g >> 3) & 3;
        const int j0  = ci_g & 7;          // 0 or 4
        const size_t eoff = ((((((size_t)(bbl * 9 + tap) * 4 + ct4) * 8 + cc2) * 2 + k32) * 8 + rg) * 64
                             + hi * 16 + lo) * 8 + j0;
        *(uint2*)&wmod[eoff] = pk;
    }
}

// ---------------- k5: xT[bbl][hw][ci] = bf16(x[b][ci][hw]) ---------------- (8B stores)
__global__ void k_xt(const float* __restrict__ x, unsigned short* __restrict__ xT, int b_start) {
    const int bbl = blockIdx.x;
    const int b = b_start + bbl;
    const int hw0 = blockIdx.y * 64;
    const int ci0 = blockIdx.z * 64;
    const int t = threadIdx.x;

    __shared__ float tile[64][65]; // [ci][hw], padded
    {
        const int j = t & 63, isub = t >> 6;
        for (int i = isub; i < 64; i += 4)
            tile[i][j] = x[((size_t)b * CIN + ci0 + i) * HWSZ + hw0 + j];
    }
    __syncthreads();

    const int cq = t & 15;   // ci quad within 64-chunk
    const int rs = t >> 4;   // 0..15
    for (int r = rs; r < 64; r += 16) {
        const float v0 = tile[4 * cq + 0][r];
        const float v1 = tile[4 * cq + 1][r];
        const float v2 = tile[4 * cq + 2][r];
        const float v3 = tile[4 * cq + 3][r];
        uint2 pk;
        pk.x = (unsigned int)f2bf(v0) | ((unsigned int)f2bf(v1) << 16);
        pk.y = (unsigned int)f2bf(v2) | ((unsigned int)f2bf(v3) << 16);
        *(uint2*)&xT[((size_t)bbl * HWSZ + hw0 + r) * CIN + ci0 + 4 * cq] = pk;
    }
}

// ---------------- k6: 9-tap implicit-GEMM conv; A global->reg, X in dbuf LDS ----------
// 128co x 128px tile, 4 waves. A-frags loaded straight from the pre-fragmented afrag
// (coalesced, L1/L2-hit, 1 tap ahead into a static-parity register double buffer).
// X halo tile double-buffered in LDS; ONE barrier per ci-chunk (no per-tap barriers;
// waves free-run within a cc since Xs is read-only).
#define XBUF 33792
__global__ __launch_bounds__(256, 2)
void k_conv(const unsigned short* __restrict__ xT, const unsigned short* __restrict__ afrag,
            float* __restrict__ out, int b_start, int gcount) {
    int st, ct, bbl;
    {
        const int id = blockIdx.x;
        if (gcount == 16) {
            const int xcd = id & 7;            // pin bbl's panels to one XCD L2
            const int slot = id >> 3;          // 0..255
            bbl = xcd + 8 * (slot >> 7);       // {xcd, xcd+8}
            const int rem = slot & 127;
            ct = rem >> 5;                     // 0..3
            st = rem & 31;
        } else {
            st = id & 31; ct = (id >> 5) & 3; bbl = id >> 7;
        }
    }
    const int b = b_start + bbl;
    const int r0 = st * 2;      // first output row
    const int co0 = ct * 128;

    const int t = threadIdx.x;
    const int lane = t & 63;
    const int wid = t >> 6;
    const int wrow = wid >> 1; // co half
    const int wcol = wid & 1;  // px half

    __shared__ __align__(16) unsigned char smem[2 * XBUF]; // Xs double buffer

    const f32x4 fzero = {0.f, 0.f, 0.f, 0.f};

    // zero pads (cols 0,65, both buffers) + out-of-image halo rows (both buffers)
    if (t < 128) {
        const int s = t >> 3;                    // 16 slots: buf x row x col
        unsigned char* Xb = smem + ((s >> 3) & 1) * XBUF;
        const int row = (s >> 1) & 3, col = (s & 1) ? 65 : 0;
        *(f32x4*)(Xb + (row * 66 + col) * 128 + (t & 7) * 16) = fzero;
    }
    if (r0 == 0) {
        for (int idx = t; idx < 2 * 66 * 8; idx += 256) {
            unsigned char* Xb = smem + (idx >= 66 * 8 ? XBUF : 0);
            const int k = idx % (66 * 8);
            *(f32x4*)(Xb + (k >> 3) * 128 + (k & 7) * 16) = fzero;
        }
    }
    if (r0 == 62) {
        for (int idx = t; idx < 2 * 66 * 8; idx += 256) {
            unsigned char* Xb = smem + (idx >= 66 * 8 ? XBUF : 0);
            const int k = idx % (66 * 8);
            *(f32x4*)(Xb + (3 * 66 + (k >> 3)) * 128 + (k & 7) * 16) = fzero;
        }
    }

    f32x4 acc[4][4];
#pragma unroll
    for (int i = 0; i < 4; ++i)
#pragma unroll
        for (int j = 0; j < 4; ++j) acc[i][j] = fzero;

    const size_t xTbase = (size_t)bbl * HWSZ * CIN;

    auto stageX = [&](int ccn, unsigned char* dst) {
        const int ci0 = ccn * 64;
#pragma unroll
        for (int i = 0; i < 8; ++i) {
            const int li = wid + 4 * i;      // 0..31
            const int row = li >> 3;         // 0..3
            const int c0 = 1 + (li & 7) * 8; // 1,9,...,57
            const int ih = r0 - 1 + row;
            if (ih >= 0 && ih < HH) {
                const int col = c0 + (lane >> 3);     // 1..64
                const int pxidx = row * 66 + col;
                const int kb = ((lane & 7) * 16) ^ ((pxidx & 7) << 4);
                gload_lds16((const unsigned char*)(xT + xTbase + (size_t)(ih * WW + col - 1) * CIN + ci0) + kb,
                            dst + (row * 66 + c0) * 128);
            }
        }
    };

    // A-frag loads: fully coalesced 16B/lane from the pre-fragmented layout
    auto loadA = [&](int tap2, int cc2, bf16x8 (&dst)[2][4]) {
        const unsigned short* base = afrag
            + (size_t)((((bbl * 9 + tap2) * 4 + ct) * 8 + cc2) * 2) * 4096
            + (wrow * 4) * 512 + lane * 8;
#pragma unroll
        for (int k32 = 0; k32 < 2; ++k32)
#pragma unroll
            for (int ma = 0; ma < 4; ++ma)
                dst[k32][ma] = *(const bf16x8*)(base + k32 * 4096 + ma * 512);
    };

    auto mfma_tap = [&](const unsigned char* Xcur, int dh, int dw, bf16x8 (&A)[2][4]) {
#pragma unroll
        for (int k32 = 0; k32 < 2; ++k32) {
            bf16x8 bfv[4];
#pragma unroll
            for (int nb = 0; nb < 4; ++nb) {
                const int px = wcol * 64 + nb * 16 + (lane & 15);
                const int trow = (px >> 6) + 1 + dh;   // 0..3
                const int tcol = (px & 63) + 1 + dw;   // 0..65
                const int pxidx = trow * 66 + tcol;
                const int kb = (k32 * 64 + (lane >> 4) * 16) ^ ((pxidx & 7) << 4);
                bfv[nb] = *(const bf16x8*)(Xcur + pxidx * 128 + kb);
            }
#pragma unroll
            for (int ma = 0; ma < 4; ++ma)
#pragma unroll
                for (int nb = 0; nb < 4; ++nb)
                    acc[ma][nb] = __builtin_amdgcn_mfma_f32_16x16x32_bf16(
                        A[k32][ma], bfv[nb], acc[ma][nb], 0, 0, 0);
        }
    };

    bf16x8 aE[2][4], aO[2][4];

    // prologue: X(0) staged; pads + X landed before anyone reads
    stageX(0, smem);
    asm volatile("s_waitcnt vmcnt(0) lgkmcnt(0)" ::: "memory");
    __builtin_amdgcn_s_barrier();
    loadA(0, 0, aE);   // A(g=0), g even -> aE

    for (int ccp = 0; ccp < 4; ++ccp) {
#pragma unroll
        for (int t18 = 0; t18 < 18; ++t18) {
            const int h = t18 / 9;          // static: Xs buffer = cc&1
            const int tap9 = t18 % 9;       // static
            const int cc = 2 * ccp + h;     // runtime (uniform)
            unsigned char* Xcur = smem + h * XBUF;
            unsigned char* Xnxt = smem + (1 - h) * XBUF;
            const int dh = tap9 / 3 - 1, dw = tap9 % 3 - 1;
            const int p = (h + tap9) & 1;   // static parity of g

            // issue X(cc+1) at tap 0 (ahead of this tap's A loads)
            if (tap9 == 0) {
                if (h == 0 || ccp < 3) stageX(cc + 1, Xnxt);
            }
            // issue A(g+1) into the other register set (skip only at g=71)
            {
                const int tapn = (tap9 + 1) % 9;              // static
                const int ccn = cc + (tap9 == 8 ? 1 : 0);     // runtime
                if (p == 0) {
                    if (!(t18 == 17) || ccp < 3) loadA(tapn, ccn, aO);
                } else {
                    if (!(t18 == 17) || ccp < 3) loadA(tapn, ccn, aE);
                }
            }
            // MFMA on current set (compiler schedules ds_read/MFMA/waits)
            if (p == 0) mfma_tap(Xcur, dh, dw, aE);
            else        mfma_tap(Xcur, dh, dw, aO);

            // cc boundary: Xs[1-h] fully staged & visible before next cc reads it
            if (tap9 == 8 && !(h == 1 && ccp == 3)) {
                asm volatile("s_waitcnt lgkmcnt(0)" ::: "memory");
                asm volatile("s_waitcnt vmcnt(8)" ::: "memory");  // X retired (72 A-loads issued after it)
                __builtin_amdgcn_s_barrier();
                __builtin_amdgcn_sched_barrier(0);
            }
        }
    }

    // epilogue: C/D layout col=lane&15 (px/N), row=(lane>>4)*4+reg (co/M)
#pragma unroll
    for (int ma = 0; ma < 4; ++ma) {
        const int co = co0 + wrow * 64 + ma * 16 + ((lane >> 4) << 2);
#pragma unroll
        for (int nb = 0; nb < 4; ++nb) {
            const int px = wcol * 64 + nb * 16 + (lane & 15);
            const int oh = r0 + (px >> 6);
            const int ow = px & 63;
            float* o = out + (((size_t)b * COUT + co) * HH + oh) * WW + ow;
#pragma unroll
            for (int jj = 0; jj < 4; ++jj) o[(size_t)jj * HWSZ] = acc[ma][nb][jj];
        }
    }
}

extern "C" void kernel_launch(void* const* d_in, const int* in_sizes, int n_in,
                              void* d_out, int out_size, void* d_ws, size_t ws_size,
                              hipStream_t stream) {
    (void)in_sizes; (void)n_in; (void)out_size;
    const float* x     = (const float*)d_in[0];
    const float* w     = (const float*)d_in[1];
    const float* convw = (const float*)d_in[2];
    const float* mod_w = (const float*)d_in[3];
    const float* mod_b = (const float*)d_in[4];
    float* out = (float*)d_out;

    unsigned char* ws = (unsigned char*)d_ws;
    const size_t OFF_STYLE = 0;
    const size_t OFF_S2 = 32768;
    const size_t OFF_D = OFF_S2 + 1048576;
    const size_t OFF_BIG = OFF_D + 32768;
    const size_t PER_B_W = (size_t)9 * COUT * CIN * 2; // 4,718,592 B
    const size_t PER_B_X = (size_t)HWSZ * CIN * 2;     // 4,194,304 B
    const size_t PER_B = PER_B_W + PER_B_X;

    if (ws_size < OFF_BIG + PER_B) return; // cannot run
    const size_t avail = ws_size - OFF_BIG;
    const int G = (avail >= 16 * PER_B) ? 16 : (avail >= 4 * PER_B ? 4 : 1);

    float* style = (float*)(ws + OFF_STYLE);
    float* s2    = (float*)(ws + OFF_S2);
    float* dd    = (float*)(ws + OFF_D);
    unsigned short* wmod = (unsigned short*)(ws + OFF_BIG);
    unsigned short* xT   = (unsigned short*)(ws + OFF_BIG + (size_t)G * PER_B_W);

    k_style<<<dim3(16), dim3(256), 0, stream>>>(w, mod_w, mod_b, style);
    k_s2<<<dim3(1024), dim3(256), 0, stream>>>(convw, s2);
    k_demod<<<dim3(16), dim3(256), 0, stream>>>(style, s2, dd);

    for (int b0 = 0; b0 < NB; b0 += G) {
        k_wmod<<<dim3(9, 8, 4), dim3(256), 0, stream>>>(convw, style, dd, wmod, b0, G);
        k_xt<<<dim3(G, 64, 8), dim3(256), 0, stream>>>(x, xT, b0);
        k_conv<<<dim3(32 * 4 * G), dim3(256), 0, stream>>>(xT, wmod, out, b0, G);
    }
}

// Round 9
// 469.115 us; speedup vs baseline: 1.2702x; 1.2702x over previous
//
#include <hip/hip_runtime.h>
#include <hip/hip_bf16.h>

#define NB    16
#define CIN   512
#define COUT  512
#define HH    64
#define WW    64
#define HWSZ  4096
#define WDIMN 512

typedef __attribute__((ext_vector_type(8))) short bf16x8;
typedef __attribute__((ext_vector_type(4))) float f32x4;

__device__ __forceinline__ unsigned short f2bf(float f) {
    unsigned int u = __float_as_uint(f);
    unsigned int lsb = (u >> 16) & 1u;
    u += 0x7fffu + lsb;               // round-to-nearest-even (finite inputs)
    return (unsigned short)(u >> 16);
}

__device__ __forceinline__ void gload_lds16(const void* g, void* l) {
    __builtin_amdgcn_global_load_lds(
        (const __attribute__((address_space(1))) unsigned char*)g,
        (__attribute__((address_space(3))) unsigned char*)l,
        16, 0, 0);
}

// ---------------- k1: style[b][ci] = coef_mod * (w @ mod_w) + mod_b + 1 ----------------
__global__ void k_style(const float* __restrict__ w, const float* __restrict__ mod_w,
                        const float* __restrict__ mod_b, float* __restrict__ style) {
    const int b = blockIdx.x, t = threadIdx.x;
    __shared__ float wl[WDIMN];
    wl[t] = w[b * WDIMN + t];
    wl[t + 256] = w[b * WDIMN + t + 256];
    __syncthreads();
    float a0 = 0.f, a1 = 0.f;
    const int c0 = t, c1 = t + 256;
    for (int j = 0; j < WDIMN; ++j) {
        const float wj = wl[j];
        a0 += wj * mod_w[j * CIN + c0];
        a1 += wj * mod_w[j * CIN + c1];
    }
    const float coef = 0.044194173824159216f; // 1/sqrt(512)
    style[b * CIN + c0] = coef * a0 + mod_b[c0] + 1.0f;
    style[b * CIN + c1] = coef * a1 + mod_b[c1] + 1.0f;
}

// ---------------- k2: s2[ci][co] = sum_taps conv_w^2 ----------------
__global__ void k_s2(const float* __restrict__ cw, float* __restrict__ s2) {
    const int i = blockIdx.x * 256 + threadIdx.x; // [ci*512+co]
    float a = 0.f;
#pragma unroll
    for (int tap = 0; tap < 9; ++tap) {
        const float v = cw[tap * (CIN * COUT) + i];
        a += v * v;
    }
    s2[i] = a;
}

// ---------------- k3: d[b][co] = rsqrt(coef^2 * sum_ci style^2 * s2 + 1e-8) ----------------
__global__ void k_demod(const float* __restrict__ style, const float* __restrict__ s2,
                        float* __restrict__ dd) {
    const int b = blockIdx.x, t = threadIdx.x;
    __shared__ float st2[CIN];
    {
        const float s0 = style[b * CIN + t], s1 = style[b * CIN + t + 256];
        st2[t] = s0 * s0;
        st2[t + 256] = s1 * s1;
    }
    __syncthreads();
    float a0 = 0.f, a1 = 0.f;
    for (int ci = 0; ci < CIN; ++ci) {
        const float sv = st2[ci];
        a0 += sv * s2[ci * COUT + t];
        a1 += sv * s2[ci * COUT + t + 256];
    }
    const float c2 = 1.0f / 4608.0f; // coef_conv^2
    dd[b * COUT + t] = rsqrtf(c2 * a0 + 1e-8f);
    dd[b * COUT + t + 256] = rsqrtf(c2 * a1 + 1e-8f);
}

// ---------------- k4: wmod[bbl][tap][co][ci] = bf16(conv_w * coef * style * d) ----------------
// 8B stores, style staged in LDS. (Round-6 proven version.)
__global__ void k_wmod(const float* __restrict__ cw, const float* __restrict__ style,
                       const float* __restrict__ dd, unsigned short* __restrict__ wmod,
                       int b_start, int gcount) {
    const int tap = blockIdx.x;
    const int co0 = blockIdx.y * 64;
    const int ci0 = blockIdx.z * 128;
    const int t = threadIdx.x;

    __shared__ float tile[128][65]; // [ci][co], padded
    __shared__ float sst[16 * 128]; // style slice [bbl][128-ci-chunk]
    {
        const int j = t & 63, isub = t >> 6;
        for (int i = isub; i < 128; i += 4)
            tile[i][j] = cw[(size_t)tap * CIN * COUT + (size_t)(ci0 + i) * COUT + co0 + j];
    }
    for (int i = t; i < gcount * 128; i += 256)
        sst[i] = style[(b_start + (i >> 7)) * CIN + ci0 + (i & 127)];
    __syncthreads();

    const float coef = 0.014731391274719736f; // 1/sqrt(4608)
    const int cq = t & 31;        // ci quad: ci = ci0 + 4*cq + k
    const int rsub = t >> 5;      // 0..7
    const int totrows = gcount * 64;
    for (int g = rsub; g < totrows; g += 8) {
        const int bbl = g >> 6;
        const int co_r = g & 63;
        const int bg = b_start + bbl;
        const float dv = dd[bg * COUT + co0 + co_r] * coef;
        const float v0 = tile[4 * cq + 0][co_r] * sst[bbl * 128 + 4 * cq + 0] * dv;
        const float v1 = tile[4 * cq + 1][co_r] * sst[bbl * 128 + 4 * cq + 1] * dv;
        const float v2 = tile[4 * cq + 2][co_r] * sst[bbl * 128 + 4 * cq + 2] * dv;
        const float v3 = tile[4 * cq + 3][co_r] * sst[bbl * 128 + 4 * cq + 3] * dv;
        uint2 pk;
        pk.x = (unsigned int)f2bf(v0) | ((unsigned int)f2bf(v1) << 16);
        pk.y = (unsigned int)f2bf(v2) | ((unsigned int)f2bf(v3) << 16);
        *(uint2*)&wmod[((size_t)(bbl * 9 + tap) * COUT + co0 + co_r) * CIN + ci0 + 4 * cq] = pk;
    }
}

// ---------------- k6: 9-tap implicit-GEMM conv, fused x-transpose staging --------------
// Round-6 proven loop (128co x 128px full-width tile, A dbuf via gload_lds, counted-vmcnt
// per-tap sync, XCD-pinned grid) with k_xt FUSED: X staging reads x (f32 NCHW, coalesced
// 64x4B per (row,ci)), converts to bf16 in-register, packs 4 ci, and ds_write_b64s into
// the same XOR-swizzled Xs layout the B-reads use. Sync structure unchanged except an
// added lgkmcnt(0) before the tap-8 barrier to publish the ds_writes.
__global__ __launch_bounds__(256, 2)
void k_conv(const float* __restrict__ x, const unsigned short* __restrict__ wmod,
            float* __restrict__ out, int b_start, int gcount) {
    int st, ct, bbl;
    {
        const int id = blockIdx.x;
        if (gcount == 16) {
            // hw assigns XCD = linear_id % 8; pin bbl (and its x/wmod panels) to one XCD
            const int xcd = id & 7;
            const int slot = id >> 3;          // 0..255
            bbl = xcd + 8 * (slot >> 7);       // {xcd, xcd+8}
            const int rem = slot & 127;
            ct = rem >> 5;                     // 0..3
            st = rem & 31;
        } else {
            st = id & 31; ct = (id >> 5) & 3; bbl = id >> 7;
        }
    }
    const int b = b_start + bbl;
    const int r0 = st * 2;      // first output row
    const int co0 = ct * 128;

    const int t = threadIdx.x;
    const int lane = t & 63;
    const int wid = t >> 6;
    const int wrow = wid >> 1; // co half
    const int wcol = wid & 1;  // px half

    __shared__ __align__(16) unsigned char smem[4 * 66 * 128 + 2 * 128 * 128];
    unsigned char* Xs = smem;                 // [(row*66+col)][128B], XOR-swizzled
    unsigned char* As = smem + 4 * 66 * 128;  // 2 x [co][128B]

    const f32x4 fzero = {0.f, 0.f, 0.f, 0.f};

    // one-time zeroing: pad columns (0, 65) for all 4 rows, and out-of-image halo rows
    if (t < 64) {
        const int s = t >> 3;                    // 8 pad slots
        const int row = s >> 1, col = (s & 1) ? 65 : 0;
        *(f32x4*)(Xs + (row * 66 + col) * 128 + (t & 7) * 16) = fzero;
    }
    if (r0 == 0) {
        for (int idx = t; idx < 66 * 8; idx += 256)
            *(f32x4*)(Xs + (idx >> 3) * 128 + (idx & 7) * 16) = fzero;
    }
    if (r0 == 62) {
        for (int idx = t; idx < 66 * 8; idx += 256)
            *(f32x4*)(Xs + (3 * 66 + (idx >> 3)) * 128 + (idx & 7) * 16) = fzero;
    }

    f32x4 acc[4][4];
#pragma unroll
    for (int i = 0; i < 4; ++i)
#pragma unroll
        for (int j = 0; j < 4; ++j) acc[i][j] = fzero;

    auto stageA = [&](int gidx) { // load A(gidx) into slot gidx&1 (gload_lds, src pre-swizzled)
        const int tap2 = gidx % 9, cc2 = gidx / 9;
        const unsigned short* gb = wmod + ((size_t)(bbl * 9 + tap2) * COUT + co0) * CIN + cc2 * 64;
        unsigned char* dbase = As + (gidx & 1) * 16384;
#pragma unroll
        for (int i = 0; i < 4; ++i) {
            const int la = wid + 4 * i;                 // 0..15
            const int row = la * 8 + (lane >> 3);       // 0..127 (co)
            const int kb = ((lane & 7) * 16) ^ ((row & 7) << 4);
            gload_lds16((const unsigned char*)(gb + (size_t)row * CIN) + kb,
                        dbase + la * 1024);
        }
    };

    // FUSED X staging: read x f32 NCHW (coalesced), cvt->bf16, pack 4 ci, swizzled ds_write
    auto stageX = [&](int ccn) {
        const int ci0 = ccn * 64;
#pragma unroll
        for (int u = 0; u < 16; ++u) {
            const int row = u & 3;                 // 0..3
            const int q = (u >> 2) * 4 + wid;      // ci quad 0..15 (wave-interleaved)
            const int ih = r0 - 1 + row;
            if (ih >= 0 && ih < HH) {
                const float* xp = x + ((size_t)(b * CIN + ci0 + 4 * q) * HH + ih) * WW + lane;
                const float v0 = xp[0];
                const float v1 = xp[HWSZ];
                const float v2 = xp[2 * HWSZ];
                const float v3 = xp[3 * HWSZ];
                uint2 pk;
                pk.x = (unsigned int)f2bf(v0) | ((unsigned int)f2bf(v1) << 16);
                pk.y = (unsigned int)f2bf(v2) | ((unsigned int)f2bf(v3) << 16);
                const int pxidx = row * 66 + 1 + lane;          // col = 1+iw
                const int off8 = (8 * q) ^ ((pxidx & 7) << 4);  // same involution as reads
                *(uint2*)(Xs + pxidx * 128 + off8) = pk;
            }
        }
    };

    // prologue: X(0) (self-draining loads + ds_writes), A(0), A(1); publish writes; barrier
    stageX(0);
    stageA(0);
    stageA(1);
    asm volatile("s_waitcnt vmcnt(4) lgkmcnt(0)" ::: "memory"); // A(0) landed; A(1) may fly
    __builtin_amdgcn_s_barrier();

    for (int cc = 0; cc < 8; ++cc) {
#pragma unroll
        for (int tap = 0; tap < 9; ++tap) {
            const int g = cc * 9 + tap;
            const unsigned char* Ab = As + (g & 1) * 16384;
            const int dh = tap / 3 - 1, dw = tap % 3 - 1;

            // ds_read + MFMA, compiler-scheduled (fine-grained lgkmcnt interleave)
#pragma unroll
            for (int k32 = 0; k32 < 2; ++k32) {
                bf16x8 af[4], bfv[4];
#pragma unroll
                for (int ma = 0; ma < 4; ++ma) {
                    const int co_r = wrow * 64 + ma * 16 + (lane & 15);
                    const int kb = (k32 * 64 + (lane >> 4) * 16) ^ ((co_r & 7) << 4);
                    af[ma] = *(const bf16x8*)(Ab + co_r * 128 + kb);
                }
#pragma unroll
                for (int nb = 0; nb < 4; ++nb) {
                    const int px = wcol * 64 + nb * 16 + (lane & 15);
                    const int trow = (px >> 6) + 1 + dh;   // 0..3
                    const int tcol = (px & 63) + 1 + dw;   // 0..65
                    const int pxidx = trow * 66 + tcol;
                    const int kb = (k32 * 64 + (lane >> 4) * 16) ^ ((pxidx & 7) << 4);
                    bfv[nb] = *(const bf16x8*)(Xs + pxidx * 128 + kb);
                }
#pragma unroll
                for (int ma = 0; ma < 4; ++ma)
#pragma unroll
                    for (int nb = 0; nb < 4; ++nb)
                        acc[ma][nb] = __builtin_amdgcn_mfma_f32_16x16x32_bf16(
                            af[ma], bfv[nb], acc[ma][nb], 0, 0, 0);
            }

            // barrier #1: this wave's LDS reads retired; all waves done with slot/Xs
            asm volatile("s_waitcnt lgkmcnt(0)" ::: "memory");
            __builtin_amdgcn_s_barrier();

            // prefetch/stage: X(cc+1) (loads+cvt+ds_writes), then A(g+2) into slot g&1
            if (tap == 8 && cc < 7) stageX(cc + 1);
            if (g < 70) stageA(g + 2);

            // wait: A(g+1) landed; A(g+2) stays in flight; publish X ds_writes at tap 8
            if (g == 70) asm volatile("s_waitcnt vmcnt(0)" ::: "memory");
            else         asm volatile("s_waitcnt vmcnt(4)" ::: "memory");
            if (tap == 8) asm volatile("s_waitcnt lgkmcnt(0)" ::: "memory");
            __builtin_amdgcn_s_barrier();   // barrier #2: next operands visible to all
        }
    }

    // epilogue: C/D layout col=lane&15 (px/N), row=(lane>>4)*4+reg (co/M)
#pragma unroll
    for (int ma = 0; ma < 4; ++ma) {
        const int co = co0 + wrow * 64 + ma * 16 + ((lane >> 4) << 2);
#pragma unroll
        for (int nb = 0; nb < 4; ++nb) {
            const int px = wcol * 64 + nb * 16 + (lane & 15);
            const int oh = r0 + (px >> 6);
            const int ow = px & 63;
            float* o = out + (((size_t)b * COUT + co) * HH + oh) * WW + ow;
#pragma unroll
            for (int jj = 0; jj < 4; ++jj) o[(size_t)jj * HWSZ] = acc[ma][nb][jj];
        }
    }
}

extern "C" void kernel_launch(void* const* d_in, const int* in_sizes, int n_in,
                              void* d_out, int out_size, void* d_ws, size_t ws_size,
                              hipStream_t stream) {
    (void)in_sizes; (void)n_in; (void)out_size;
    const float* x     = (const float*)d_in[0];
    const float* w     = (const float*)d_in[1];
    const float* convw = (const float*)d_in[2];
    const float* mod_w = (const float*)d_in[3];
    const float* mod_b = (const float*)d_in[4];
    float* out = (float*)d_out;

    unsigned char* ws = (unsigned char*)d_ws;
    const size_t OFF_STYLE = 0;
    const size_t OFF_S2 = 32768;
    const size_t OFF_D = OFF_S2 + 1048576;
    const size_t OFF_BIG = OFF_D + 32768;
    const size_t PER_B_W = (size_t)9 * COUT * CIN * 2; // 4,718,592 B

    if (ws_size < OFF_BIG + PER_B_W) return; // cannot run
    const size_t avail = ws_size - OFF_BIG;
    const int G = (avail >= 16 * PER_B_W) ? 16 : (avail >= 4 * PER_B_W ? 4 : 1);

    float* style = (float*)(ws + OFF_STYLE);
    float* s2    = (float*)(ws + OFF_S2);
    float* dd    = (float*)(ws + OFF_D);
    unsigned short* wmod = (unsigned short*)(ws + OFF_BIG);

    k_style<<<dim3(16), dim3(256), 0, stream>>>(w, mod_w, mod_b, style);
    k_s2<<<dim3(1024), dim3(256), 0, stream>>>(convw, s2);
    k_demod<<<dim3(16), dim3(256), 0, stream>>>(style, s2, dd);

    for (int b0 = 0; b0 < NB; b0 += G) {
        k_wmod<<<dim3(9, 8, 4), dim3(256), 0, stream>>>(convw, style, dd, wmod, b0, G);
        k_conv<<<dim3(32 * 4 * G), dim3(256), 0, stream>>>(x, wmod, out, b0, G);
    }
}